// Round 10
// baseline (162.305 us; speedup 1.0000x reference)
//
#include <hip/hip_runtime.h>
#include <math.h>

#define NI 100000
#define NO 50000
#define NE 100000
#define NB (NI + NO)          // 150000 combined dst bins
#define TOTE (2 * NE)         // 200000

// ---- ws layout (4B units) ----
#define OFF_WFRAG   0         // 9216 dwords = 2304 uint4
#define OFF_Y2Z2    9216      // 50000 x 16 floats = 800000 (64B-aligned rows)
#define OFF_HEAD    809216    // 150016 ints
#define OFF_NXT     959232    // 200000 ints
#define OFF_MSG     1159232   // bf16 msg: TOTE x 32 ushort = 3200000 float-slots
// total ~17.4 MB

static constexpr int B_EDGE2 = (NE + 511) / 512;       // 196 (512 edges/block)
static constexpr int B_IND  = (NI + 255) / 256;        // 391
static constexpr int B_ORG  = (NO + 255) / 256;        // 196
static constexpr int B_INIT = (NB + 2304 + 255) / 256; // 596

typedef __attribute__((ext_vector_type(8))) short short8;
typedef __attribute__((ext_vector_type(4))) float f32x4;

__device__ __forceinline__ float sigmoidf_fast(float x) {
    return 1.0f / (1.0f + __expf(-x));
}
__device__ __forceinline__ unsigned f2bf(float f) {   // RTNE to bf16 (low 16 bits)
    unsigned u = __float_as_uint(f);
    return (u + 0x7FFFu + ((u >> 16) & 1u)) >> 16;
}
__device__ __forceinline__ float bflo(unsigned u) { return __uint_as_float(u << 16); }
__device__ __forceinline__ float bfhi(unsigned u) { return __uint_as_float(u & 0xFFFF0000u); }
__device__ __forceinline__ unsigned pack_trunc(float lo, float hi) {
    return __builtin_amdgcn_perm(__float_as_uint(hi), __float_as_uint(lo), 0x07060302u);
}

// ---------------------------------------------------------------- init: head=-1 + MFMA weight-frag prep
// Frag layout (16x16x32 bf16, verified R4/R8): lane&15 = non-K index,
// quad = K-chunk (k = quad*8 + j, bf16 pairs (k,k+1) per dword).
__global__ __launch_bounds__(256) void k_init(
    const float* __restrict__ Wm_oi, const float* __restrict__ bm_oi,
    const float* __restrict__ Wm_io, const float* __restrict__ bm_io,
    float* __restrict__ ws)
{
    int idx = blockIdx.x * 256 + threadIdx.x;
    int* head = (int*)(ws + OFF_HEAD);
    if (idx < NB) {
        head[idx] = -1;
    } else {
        int u = idx - NB;                    // [0, 2304)
        if (u >= 2304) return;
        int rel = u >= 1152;                 // 0 = oi, 1 = io
        int v = u - rel * 1152;
        int lane = v & 63;
        int fi = v >> 6;                     // 0..17
        int a = fi >> 1;                     // 0..8
        int nt = fi & 1;
        int quad = lane >> 4;
        int n = nt * 16 + (lane & 15);       // output index o
        const float* Wm = rel ? Wm_io : Wm_oi;
        const float* bm = rel ? bm_io : bm_oi;
        unsigned pk[4];
        #pragma unroll
        for (int d = 0; d < 4; d++) {
            int k0 = quad * 8 + 2 * d;
            float vlo = (a < 8) ? Wm[a * 1024 + k0 * 32 + n]       : bm[k0 * 32 + n];
            float vhi = (a < 8) ? Wm[a * 1024 + (k0 + 1) * 32 + n] : bm[(k0 + 1) * 32 + n];
            pk[d] = f2bf(vlo) | (f2bf(vhi) << 16);
        }
        uint4* wf = (uint4*)(ws + OFF_WFRAG);
        wf[((rel * 9 + a) * 2 + nt) * 64 + lane] = make_uint4(pk[0], pk[1], pk[2], pk[3]);
    }
}

// ---------------------------------------------------------------- edge messages via MFMA (swapped operands), 512 edges/block
__global__ __launch_bounds__(256) void k_msg(
    const int* __restrict__ src_oi, const int* __restrict__ dst_oi, const float* __restrict__ attr_oi,
    const int* __restrict__ src_io, const int* __restrict__ dst_io, const float* __restrict__ attr_io,
    const float* __restrict__ x_ind, const float* __restrict__ x_org,
    float* __restrict__ ws)
{
    __shared__ uint4 xstage[4][256];      // 16 KB: [wave][kchunk*64 + wave-local edge]

    int* head = (int*)(ws + OFF_HEAD);
    int* nxt  = (int*)(ws + OFF_NXT);
    unsigned short* msgb = (unsigned short*)(ws + OFF_MSG);

    bool is_io = blockIdx.x >= B_EDGE2;
    int blockStart = is_io ? (NE + ((int)blockIdx.x - B_EDGE2) * 512) : ((int)blockIdx.x * 512);
    int relEnd = is_io ? TOTE : NE;
    int tid = threadIdx.x;
    int wave = tid >> 6, lane = tid & 63, quad = lane >> 4;

    const int*   srcA  = is_io ? src_io : src_oi;
    const int*   dstA  = is_io ? dst_io : dst_oi;
    const float* attrA = is_io ? attr_io : attr_oi;
    const float* xsrc  = is_io ? x_ind : x_org;

    // weight fragments (A operand: m = o) — loaded once, reused across both passes
    const uint4* wfr = ((const uint4*)(ws + OFF_WFRAG)) + (is_io ? 1152 : 0);
    uint4 wf[9][2];
    #pragma unroll
    for (int a = 0; a < 9; a++) {
        #pragma unroll
        for (int nt = 0; nt < 2; nt++)
            wf[a][nt] = wfr[((a * 2 + nt) * 64) + lane];
    }

    f32x4 zero4 = {0.f, 0.f, 0.f, 0.f};
    #pragma unroll 1
    for (int pass = 0; pass < 2; pass++) {
        int base = blockStart + pass * 256;
        int p = base + tid;                // own global edge-slot (also msg row)
        bool act = p < relEnd;
        int e = p - (is_io ? NE : 0);      // relation-local edge id

        float ar[9];
        ar[8] = 1.0f;
        if (act) {
            int s = srcA[e];
            {
                const float4* ap = (const float4*)(attrA + e * 8);
                float4 v0 = ap[0], v1 = ap[1];
                ar[0] = v0.x; ar[1] = v0.y; ar[2] = v0.z; ar[3] = v0.w;
                ar[4] = v1.x; ar[5] = v1.y; ar[6] = v1.z; ar[7] = v1.w;
            }
            const float4* xp = (const float4*)(xsrc + s * 32);
            #pragma unroll
            for (int q = 0; q < 4; q++) {
                float4 v0 = xp[2 * q], v1 = xp[2 * q + 1];
                uint4 pk;
                pk.x = pack_trunc(v0.x, v0.y);
                pk.y = pack_trunc(v0.z, v0.w);
                pk.z = pack_trunc(v1.x, v1.y);
                pk.w = pack_trunc(v1.z, v1.w);
                xstage[wave][q * 64 + lane] = pk;
            }
            // linked-list insert (traversed in later kernels)
            int cd = is_io ? (NI + dstA[e]) : dstA[e];
            int old = atomicExch(&head[cd], p);
            nxt[p] = old;
        }
        // per-wave LDS: in-order DS pipe + compiler lgkmcnt waits give write->read ordering

        #pragma unroll
        for (int mtile = 0; mtile < 4; mtile++) {
            // B-frag: x of edge (wave-local) mtile*16+(lane&15)
            uint4 braw = xstage[wave][quad * 64 + mtile * 16 + (lane & 15)];
            short8 bx = *(short8*)&braw;
            float mm0[4] = {0.f, 0.f, 0.f, 0.f};
            float mm1[4] = {0.f, 0.f, 0.f, 0.f};
            #pragma unroll
            for (int a = 0; a < 9; a++) {
                // D[m=o][n=edge]: col = edge -> attr is per-column constant
                f32x4 t0 = __builtin_amdgcn_mfma_f32_16x16x32_bf16(*(short8*)&wf[a][0], bx, zero4, 0, 0, 0);
                f32x4 t1 = __builtin_amdgcn_mfma_f32_16x16x32_bf16(*(short8*)&wf[a][1], bx, zero4, 0, 0, 0);
                float av = __shfl(ar[a], mtile * 16 + (lane & 15), 64);
                #pragma unroll
                for (int r = 0; r < 4; r++) {
                    mm0[r] = fmaf(av, t0[r], mm0[r]);
                    mm1[r] = fmaf(av, t1[r], mm1[r]);
                }
            }
            // dense bf16 store: rows o = quad*4+r (t0) and 16+quad*4+r (t1) of edge ecol
            int ecol = base + wave * 64 + mtile * 16 + (lane & 15);
            if (ecol < relEnd) {
                unsigned d0 = f2bf(mm0[0]) | (f2bf(mm0[1]) << 16);
                unsigned d1 = f2bf(mm0[2]) | (f2bf(mm0[3]) << 16);
                unsigned d2 = f2bf(mm1[0]) | (f2bf(mm1[1]) << 16);
                unsigned d3 = f2bf(mm1[2]) | (f2bf(mm1[3]) << 16);
                unsigned short* mrow = msgb + (size_t)ecol * 32;
                *(uint2*)(mrow + quad * 4)      = make_uint2(d0, d1);
                *(uint2*)(mrow + 16 + quad * 4) = make_uint2(d2, d3);
            }
        }
    }
}

// ---------------------------------------------------------------- unpack-add one bf16 msg row (64 B) into fp32 acc
__device__ __forceinline__ void add_msg_row(const unsigned short* mrow, float* ms) {
    const uint4* mr = (const uint4*)mrow;
    uint4 v0 = mr[0], v1 = mr[1], v2 = mr[2], v3 = mr[3];
    ms[0]  += bflo(v0.x); ms[1]  += bfhi(v0.x); ms[2]  += bflo(v0.y); ms[3]  += bfhi(v0.y);
    ms[4]  += bflo(v0.z); ms[5]  += bfhi(v0.z); ms[6]  += bflo(v0.w); ms[7]  += bfhi(v0.w);
    ms[8]  += bflo(v1.x); ms[9]  += bfhi(v1.x); ms[10] += bflo(v1.y); ms[11] += bfhi(v1.y);
    ms[12] += bflo(v1.z); ms[13] += bfhi(v1.z); ms[14] += bflo(v1.w); ms[15] += bfhi(v1.w);
    ms[16] += bflo(v2.x); ms[17] += bfhi(v2.x); ms[18] += bflo(v2.y); ms[19] += bfhi(v2.y);
    ms[20] += bflo(v2.z); ms[21] += bfhi(v2.z); ms[22] += bflo(v2.w); ms[23] += bfhi(v2.w);
    ms[24] += bflo(v3.x); ms[25] += bfhi(v3.x); ms[26] += bflo(v3.y); ms[27] += bfhi(v3.y);
    ms[28] += bflo(v3.z); ms[29] += bfhi(v3.z); ms[30] += bflo(v3.w); ms[31] += bfhi(v3.w);
}

// ---------------------------------------------------------------- org nodes: walk list, finish L1, prep L2
__global__ __launch_bounds__(256) void k_org(
    const float* __restrict__ x_org, const float* __restrict__ ws,
    const float* __restrict__ Wr_io, const float* __restrict__ b_io,
    const float* __restrict__ Wm2, const float* __restrict__ bm2,
    float* __restrict__ y2z2)
{
    int n = blockIdx.x * 256 + threadIdx.x;
    if (n >= NO) return;
    const int* head = (const int*)(ws + OFF_HEAD);
    const int* nxt  = (const int*)(ws + OFF_NXT);
    const unsigned short* msgb = (const unsigned short*)(ws + OFF_MSG);

    // issue head + dense x loads first so the pointer-chase overlaps them
    int e0 = head[NI + n];
    float xr[32];
    const float4* xp = (const float4*)(x_org + n * 32);
    #pragma unroll
    for (int q = 0; q < 8; q++) {
        float4 v = xp[q];
        xr[q * 4 + 0] = v.x; xr[q * 4 + 1] = v.y; xr[q * 4 + 2] = v.z; xr[q * 4 + 3] = v.w;
    }
    float ms[32];
    #pragma unroll
    for (int o = 0; o < 32; o++) ms[o] = 0.0f;
    for (int e = e0; e != -1; e = nxt[e])
        add_msg_row(msgb + (size_t)e * 32, ms);

    float h[32];
    #pragma unroll 4
    for (int o = 0; o < 32; o++) {
        float s = b_io[o] + ms[o];
        #pragma unroll
        for (int i = 0; i < 32; i++) s = fmaf(xr[i], Wr_io[i * 32 + o], s);   // wave-uniform -> s_load
        h[o] = sigmoidf_fast(s);
    }
    float yz[9];
    float z2 = 0.0f;
    #pragma unroll
    for (int i = 0; i < 32; i++) z2 = fmaf(h[i], bm2[i], z2);
    yz[0] = z2;
    #pragma unroll
    for (int a = 0; a < 8; a++) {
        float s = 0.0f;
        #pragma unroll
        for (int i = 0; i < 32; i++) s = fmaf(h[i], Wm2[a * 32 + i], s);
        yz[1 + a] = s;
    }
    float* yrow = y2z2 + (size_t)n * 16;   // padded, 64B-aligned row
    *(float4*)(yrow)     = make_float4(yz[0], yz[1], yz[2], yz[3]);
    *(float4*)(yrow + 4) = make_float4(yz[4], yz[5], yz[6], yz[7]);
    yrow[8] = yz[8];
}

// ---------------------------------------------------------------- indivi nodes: single walk (L1 sum + L2 msg), finish, out
__global__ __launch_bounds__(256) void k_out(
    const float* __restrict__ x_ind, const float* __restrict__ ws,
    const float* __restrict__ Wr_oi, const float* __restrict__ b_oi,
    const int* __restrict__ src_oi, const float* __restrict__ attr_oi,
    const float* __restrict__ Wr2, const float* __restrict__ b2,
    const float* __restrict__ y2z2,
    float* __restrict__ out)
{
    int d = blockIdx.x * 256 + threadIdx.x;
    if (d >= NI) return;
    const int* head = (const int*)(ws + OFF_HEAD);
    const int* nxt  = (const int*)(ws + OFF_NXT);
    const unsigned short* msgb = (const unsigned short*)(ws + OFF_MSG);

    // issue head + dense x loads first so the pointer-chase overlaps them
    int e0 = head[d];
    float xr[32];
    const float4* xp = (const float4*)(x_ind + d * 32);
    #pragma unroll
    for (int q = 0; q < 8; q++) {
        float4 v = xp[q];
        xr[q * 4 + 0] = v.x; xr[q * 4 + 1] = v.y; xr[q * 4 + 2] = v.z; xr[q * 4 + 3] = v.w;
    }

    float ms[32];
    #pragma unroll
    for (int o = 0; o < 32; o++) ms[o] = 0.0f;
    float m2acc = 0.0f;
    for (int e = e0; e != -1; e = nxt[e]) {
        add_msg_row(msgb + (size_t)e * 32, ms);
        // layer-2 message for this edge (e < NE, oi relation)
        int s = src_oi[e];
        const float* yrow = y2z2 + (size_t)s * 16;   // one aligned 64B line
        float4 v  = *(const float4*)(yrow);          // {z2, y0, y1, y2}
        float4 v2 = *(const float4*)(yrow + 4);      // {y3, y4, y5, y6}
        float  y7 = yrow[8];
        const float4* ap = (const float4*)(attr_oi + e * 8);
        float4 a0 = ap[0], a1 = ap[1];
        float m = v.x;
        m = fmaf(a0.x, v.y,  m); m = fmaf(a0.y, v.z,  m);
        m = fmaf(a0.z, v.w,  m); m = fmaf(a0.w, v2.x, m);
        m = fmaf(a1.x, v2.y, m); m = fmaf(a1.y, v2.z, m);
        m = fmaf(a1.z, v2.w, m); m = fmaf(a1.w, y7,   m);
        m2acc += m;
    }
    float t = b2[0] + m2acc;
    #pragma unroll 4
    for (int o = 0; o < 32; o++) {
        float s = b_oi[o] + ms[o];
        #pragma unroll
        for (int i = 0; i < 32; i++) s = fmaf(xr[i], Wr_oi[i * 32 + o], s);   // wave-uniform -> s_load
        t = fmaf(sigmoidf_fast(s), Wr2[o], t);
    }
    out[d] = sigmoidf_fast(t);
}

// ---------------------------------------------------------------- launch
extern "C" void kernel_launch(void* const* d_in, const int* in_sizes, int n_in,
                              void* d_out, int out_size, void* d_ws, size_t ws_size,
                              hipStream_t stream)
{
    const float* x_ind   = (const float*)d_in[0];
    const float* x_org   = (const float*)d_in[1];
    const int*   src_oi  = (const int*)d_in[2];
    const int*   dst_oi  = (const int*)d_in[3];
    const float* attr_oi = (const float*)d_in[4];
    const int*   src_io  = (const int*)d_in[5];
    const int*   dst_io  = (const int*)d_in[6];
    const float* attr_io = (const float*)d_in[7];
    const float* Wm_oi   = (const float*)d_in[8];
    const float* bm_oi   = (const float*)d_in[9];
    const float* Wr_oi   = (const float*)d_in[10];
    const float* b_oi    = (const float*)d_in[11];
    const float* Wm_io   = (const float*)d_in[12];
    const float* bm_io   = (const float*)d_in[13];
    const float* Wr_io   = (const float*)d_in[14];
    const float* b_io    = (const float*)d_in[15];
    const float* Wm2     = (const float*)d_in[16];
    const float* bm2     = (const float*)d_in[17];
    const float* Wr2     = (const float*)d_in[18];
    const float* b2      = (const float*)d_in[19];

    float* ws   = (float*)d_ws;
    float* y2z2 = ws + OFF_Y2Z2;
    float* out  = (float*)d_out;

    k_init<<<B_INIT, 256, 0, stream>>>(Wm_oi, bm_oi, Wm_io, bm_io, ws);

    k_msg<<<2 * B_EDGE2, 256, 0, stream>>>(
        src_oi, dst_oi, attr_oi, src_io, dst_io, attr_io, x_ind, x_org, ws);

    k_org<<<B_ORG, 256, 0, stream>>>(
        x_org, ws, Wr_io, b_io, Wm2, bm2, y2z2);

    k_out<<<B_IND, 256, 0, stream>>>(
        x_ind, ws, Wr_oi, b_oi, src_oi, attr_oi, Wr2, b2, y2z2, out);
}